// Round 9
// baseline (86.611 us; speedup 1.0000x reference)
//
#include <hip/hip_runtime.h>
#include <hip/hip_fp16.h>

typedef float v2f __attribute__((ext_vector_type(2)));

// ---------------- problem constants ----------------
#define NN    1024
#define CC    128
#define NELEM 10
#define NQ3   816
#define NQ2   136
#define NQ    968
#define KP    48     // unified p-dim: 30 (w3) + 12 (w2) + 4 (w1) + 2 pad
#define QT    11     // q-tile per fold block (88 tiles per e)
#define NTILE 88

// ---------------- workspace layout (bytes) ----------------
#define NL_OFF    0          // int[10][1024] = 40960
#define CNT_OFF   40960      // int[10]
#define CALL_OFF  524288     // half4[1280][968] = 9912320 -> 10436608
#define UHAT_OFF  10485760   // float[4][968][48] = 743424
#define F_OFF     20447232   // float4[1024][128] = 2097152 -> 22544384

__device__ __constant__ int d_OFF2[16] = {0,16,31,45,58,70,81,91,100,108,115,121,126,130,133,135};
__device__ __constant__ int d_OFF3[16] = {0,136,256,361,452,530,596,651,696,732,760,781,796,806,812,815};

// ---- setup: blocks 0..63 = sym3, 64..68 = sym2+linear, 69 = species lists ----
__global__ void k_setup(const float* __restrict__ U3_0, const float* __restrict__ U3_1,
                        const float* __restrict__ U2_0, const float* __restrict__ U2_1,
                        const float* __restrict__ U1_0, const float* __restrict__ U1_1,
                        const int* __restrict__ species,
                        float* __restrict__ uhat, int* __restrict__ nodelist,
                        int* __restrict__ counts) {
    if (blockIdx.x < 64) {
        int tid = blockIdx.x * 256 + threadIdx.x;
        int Lout = tid >> 12;
        int r = tid & 4095;
        int a = r >> 8, b = (r >> 4) & 15, m = r & 15;
        if (a > b || b > m) return;
        int q = d_OFF3[a] + (d_OFF2[b] - d_OFF2[a]) + (m - b);
        const float* U = (Lout == 0) ? U3_0 : U3_1;
        int L = (Lout == 0) ? 0 : (Lout - 1);
        int P[6][3] = {{a,b,m},{a,m,b},{b,a,m},{b,m,a},{m,a,b},{m,b,a}};
        float s[30];
#pragma unroll
        for (int p = 0; p < 30; ++p) s[p] = 0.f;
        for (int t = 0; t < 6; ++t) {
            bool dup = false;
            for (int u = 0; u < t; ++u)
                if (P[u][0] == P[t][0] && P[u][1] == P[t][1] && P[u][2] == P[t][2]) dup = true;
            if (dup) continue;
            const float* src = U + ((((L * 16 + P[t][0]) * 16 + P[t][1]) * 16 + P[t][2]) * 30);
#pragma unroll
            for (int p = 0; p < 30; ++p) s[p] += src[p];
        }
        float* dst = uhat + ((size_t)Lout * NQ + q) * KP;
#pragma unroll
        for (int p = 0; p < 30; ++p) dst[p] = s[p];
#pragma unroll
        for (int p = 30; p < KP; ++p) dst[p] = 0.f;
    } else if (blockIdx.x < 69) {
        int tid = (blockIdx.x - 64) * 256 + threadIdx.x;
        if (tid < 1024) {
            int Lout = tid >> 8;
            int r = tid & 255;
            int a = r >> 4, b = r & 15;
            if (a > b) return;
            int q = NQ3 + d_OFF2[a] + (b - a);
            const float* U = (Lout == 0) ? U2_0 : U2_1;
            int L = (Lout == 0) ? 0 : (Lout - 1);
            float* dst = uhat + ((size_t)Lout * NQ + q) * KP;
#pragma unroll
            for (int p = 0; p < 30; ++p) dst[p] = 0.f;
#pragma unroll
            for (int p = 0; p < 12; ++p) {
                float v = U[((L * 16 + a) * 16 + b) * 12 + p];
                if (a != b) v += U[((L * 16 + b) * 16 + a) * 12 + p];
                dst[30 + p] = v;
            }
#pragma unroll
            for (int p = 42; p < KP; ++p) dst[p] = 0.f;
        } else if (tid < 1024 + 64) {
            int s2 = tid - 1024;
            int Lout = s2 >> 4, i = s2 & 15;
            int q = NQ3 + NQ2 + i;
            const float* U = (Lout == 0) ? U1_0 : U1_1;
            int L = (Lout == 0) ? 0 : (Lout - 1);
            float* dst = uhat + ((size_t)Lout * NQ + q) * KP;
#pragma unroll
            for (int p = 0; p < 42; ++p) dst[p] = 0.f;
#pragma unroll
            for (int p = 0; p < 4; ++p) dst[42 + p] = U[(L * 16 + i) * 4 + p];
            dst[46] = 0.f; dst[47] = 0.f;
        }
    } else {
        __shared__ int cnt[NELEM];
        int t = threadIdx.x;
        if (t < NELEM) cnt[t] = 0;
        __syncthreads();
#pragma unroll
        for (int j = 0; j < 4; ++j) {
            int node = t * 4 + j;
            int e = species[node];
            int pos = atomicAdd(&cnt[e], 1);
            nodelist[e * NN + pos] = node;
        }
        __syncthreads();
        if (t < NELEM) counts[t] = cnt[t];
    }
}

// ---- fold: call4h[ec][q] = half4{ dot48(Uhat[L][q][:], Wcat[Lg][:]) } ----
__global__ __launch_bounds__(256) void k_fold(
    const float* __restrict__ uhat,
    const float* __restrict__ W1_0, const float* __restrict__ W2_0, const float* __restrict__ W3_0,
    const float* __restrict__ W1_1, const float* __restrict__ W2_1, const float* __restrict__ W3_1,
    uint2* __restrict__ call4h) {
    __shared__ __align__(16) float uh_lds[4][QT][KP];   // 8448 B
    int e  = blockIdx.x / NTILE;
    int qt = blockIdx.x % NTILE;
    int t = threadIdx.x;
    {
        const float4* src4 = (const float4*)uhat;
        float4* dst4 = (float4*)uh_lds;
        for (int i = t; i < 4 * QT * 12; i += 256) {
            int l = i / (QT * 12);
            int r = i - l * (QT * 12);
            int qloc = r / 12, p4 = r % 12;
            dst4[i] = src4[((size_t)l * NQ + qt * QT + qloc) * 12 + p4];
        }
    }
    int c  = t & 127;
    int qs = t >> 7;
    float wr[2][KP];
#pragma unroll
    for (int p = 0; p < 30; ++p) {
        wr[0][p] = W3_0[(e * 30 + p) * CC + c];
        wr[1][p] = W3_1[(e * 30 + p) * CC + c];
    }
#pragma unroll
    for (int p = 0; p < 12; ++p) {
        wr[0][30 + p] = W2_0[(e * 12 + p) * CC + c];
        wr[1][30 + p] = W2_1[(e * 12 + p) * CC + c];
    }
#pragma unroll
    for (int p = 0; p < 4; ++p) {
        wr[0][42 + p] = W1_0[(e * 4 + p) * CC + c];
        wr[1][42 + p] = W1_1[(e * 4 + p) * CC + c];
    }
    wr[0][46] = wr[0][47] = wr[1][46] = wr[1][47] = 0.f;
    __syncthreads();
    size_t base = ((size_t)e * CC + c) * NQ;
    for (int j = 0; j < 6; ++j) {
        int qloc = qs * 6 + j;
        if (qloc >= QT) break;
        int q = qt * QT + qloc;
        float r[4];
#pragma unroll
        for (int l = 0; l < 4; ++l) {
            const float4* up = (const float4*)uh_lds[l][qloc];
            const float* w = (l == 0) ? wr[0] : wr[1];
            float acc0 = 0.f, acc1 = 0.f, acc2 = 0.f, acc3 = 0.f;
#pragma unroll
            for (int p4 = 0; p4 < 12; ++p4) {
                float4 u = up[p4];
                acc0 = fmaf(u.x, w[p4 * 4 + 0], acc0);
                acc1 = fmaf(u.y, w[p4 * 4 + 1], acc1);
                acc2 = fmaf(u.z, w[p4 * 4 + 2], acc2);
                acc3 = fmaf(u.w, w[p4 * 4 + 3], acc3);
            }
            r[l] = (acc0 + acc1) + (acc2 + acc3);
        }
        __half2 h01 = __floats2half2_rn(r[0], r[1]);
        __half2 h23 = __floats2half2_rn(r[2], r[3]);
        uint2 v;
        v.x = *(unsigned int*)&h01;
        v.y = *(unsigned int*)&h23;
        call4h[base + q] = v;
    }
}

// ---- monomial macros: f32 coeffs from LDS; 4 nodes (2 v2f pairs) per lane ----
#define CUBIC(A0, A1) { \
    _Pragma("unroll") for (int a = (A0); a < (A1); ++a) { \
        _Pragma("unroll") for (int b = a; b < 16; ++b) { \
            v2f pabA = xvA[a] * xvA[b]; v2f pabB = xvB[a] * xvB[b]; \
            _Pragma("unroll") for (int m = b; m < 16; ++m) { \
                float4 w = cfp[q]; \
                v2f moA = pabA * xvA[m]; v2f moB = pabB * xvB[m]; \
                aA0 += moA * w.x; aA1 += moA * w.y; aA2 += moA * w.z; aA3 += moA * w.w; \
                aB0 += moB * w.x; aB1 += moB * w.y; aB2 += moB * w.z; aB3 += moB * w.w; \
                ++q; } } } }

#define QUAD(A0, A1) { \
    _Pragma("unroll") for (int a = (A0); a < (A1); ++a) { \
        _Pragma("unroll") for (int b = a; b < 16; ++b) { \
            float4 w = cfp[q]; \
            v2f moA = xvA[a] * xvA[b]; v2f moB = xvB[a] * xvB[b]; \
            aA0 += moA * w.x; aA1 += moA * w.y; aA2 += moA * w.z; aA3 += moA * w.w; \
            aB0 += moB * w.x; aB1 += moB * w.y; aB2 += moB * w.z; aB3 += moB * w.w; \
            ++q; } } }

// ---- polynomial eval: block=(e, 2 channels); 4 q-slice waves;
// ---- half-wave = channel; 4 nodes per lane (32 slots x 4) ----
// __launch_bounds__(256,1): allow up to 512 VGPR so the 2-node-pair state
// (~170 VGPR) allocates spill-free; 44KB LDS caps at 3 blocks/CU anyway.
__global__ __launch_bounds__(256, 1) void k_eval(
    const float* __restrict__ x, const int* __restrict__ nodelist,
    const int* __restrict__ counts, const uint2* __restrict__ call4h,
    float4* __restrict__ fout) {
    __shared__ __align__(16) float4 cf_lds[2][NQ + 2];   // 31040 B
    __shared__ __align__(16) v2f part[3][64][9];         // 13824 B
    int blk = blockIdx.x;            // 640 = 10 e x 64 c-pairs
    int e  = blk >> 6;
    int c0 = (blk & 63) * 2;
    int cnt = counts[e];
    int t = threadIdx.x;
    int slice = t >> 6, lane = t & 63;
    int half = lane >> 5, ls = lane & 31;
    int c = c0 + half;

    // stage + upconvert coefficients for both channels (coalesced uint2)
    const uint2* src = call4h + ((size_t)e * CC + c0) * NQ;
    for (int i = t; i < 2 * NQ; i += 256) {
        uint2 pk = src[i];
        __half2 h01 = *(__half2*)&pk.x, h23 = *(__half2*)&pk.y;
        int ch = i >= NQ;
        cf_lds[ch][i - ch * NQ] = make_float4(
            __half2float(h01.x), __half2float(h01.y),
            __half2float(h23.x), __half2float(h23.y));
    }
    __syncthreads();
    const float4* cfp = cf_lds[half];

    for (int sb = 0; sb < cnt; sb += 128) {
        int ib = sb + ls * 4;
        bool v0 = ib < cnt, v1 = ib + 1 < cnt, v2 = ib + 2 < cnt, v3 = ib + 3 < cnt;
        int n0 = v0 ? nodelist[e * NN + ib] : 0;
        int n1 = v1 ? nodelist[e * NN + ib + 1] : 0;
        int n2 = v2 ? nodelist[e * NN + ib + 2] : 0;
        int n3 = v3 ? nodelist[e * NN + ib + 3] : 0;
        const float4* xp0 = (const float4*)(x + ((size_t)n0 * CC + c) * 16);
        const float4* xp1 = (const float4*)(x + ((size_t)n1 * CC + c) * 16);
        const float4* xp2 = (const float4*)(x + ((size_t)n2 * CC + c) * 16);
        const float4* xp3 = (const float4*)(x + ((size_t)n3 * CC + c) * 16);
        float4 r0, r1, r2, r3, s0, s1, s2, s3;
        v2f xvA[16], xvB[16];
        r0 = xp0[0]; r1 = xp0[1]; r2 = xp0[2]; r3 = xp0[3];
        s0 = xp1[0]; s1 = xp1[1]; s2 = xp1[2]; s3 = xp1[3];
        xvA[0]  = v2f{r0.x, s0.x}; xvA[1]  = v2f{r0.y, s0.y};
        xvA[2]  = v2f{r0.z, s0.z}; xvA[3]  = v2f{r0.w, s0.w};
        xvA[4]  = v2f{r1.x, s1.x}; xvA[5]  = v2f{r1.y, s1.y};
        xvA[6]  = v2f{r1.z, s1.z}; xvA[7]  = v2f{r1.w, s1.w};
        xvA[8]  = v2f{r2.x, s2.x}; xvA[9]  = v2f{r2.y, s2.y};
        xvA[10] = v2f{r2.z, s2.z}; xvA[11] = v2f{r2.w, s2.w};
        xvA[12] = v2f{r3.x, s3.x}; xvA[13] = v2f{r3.y, s3.y};
        xvA[14] = v2f{r3.z, s3.z}; xvA[15] = v2f{r3.w, s3.w};
        r0 = xp2[0]; r1 = xp2[1]; r2 = xp2[2]; r3 = xp2[3];
        s0 = xp3[0]; s1 = xp3[1]; s2 = xp3[2]; s3 = xp3[3];
        xvB[0]  = v2f{r0.x, s0.x}; xvB[1]  = v2f{r0.y, s0.y};
        xvB[2]  = v2f{r0.z, s0.z}; xvB[3]  = v2f{r0.w, s0.w};
        xvB[4]  = v2f{r1.x, s1.x}; xvB[5]  = v2f{r1.y, s1.y};
        xvB[6]  = v2f{r1.z, s1.z}; xvB[7]  = v2f{r1.w, s1.w};
        xvB[8]  = v2f{r2.x, s2.x}; xvB[9]  = v2f{r2.y, s2.y};
        xvB[10] = v2f{r2.z, s2.z}; xvB[11] = v2f{r2.w, s2.w};
        xvB[12] = v2f{r3.x, s3.x}; xvB[13] = v2f{r3.y, s3.y};
        xvB[14] = v2f{r3.z, s3.z}; xvB[15] = v2f{r3.w, s3.w};
        if (!v0) {
#pragma unroll
            for (int m = 0; m < 16; ++m) xvA[m].x = 0.f;
        }
        if (!v1) {
#pragma unroll
            for (int m = 0; m < 16; ++m) xvA[m].y = 0.f;
        }
        if (!v2) {
#pragma unroll
            for (int m = 0; m < 16; ++m) xvB[m].x = 0.f;
        }
        if (!v3) {
#pragma unroll
            for (int m = 0; m < 16; ++m) xvB[m].y = 0.f;
        }
        v2f aA0 = {0.f,0.f}, aA1 = {0.f,0.f}, aA2 = {0.f,0.f}, aA3 = {0.f,0.f};
        v2f aB0 = {0.f,0.f}, aB1 = {0.f,0.f}, aB2 = {0.f,0.f}, aB3 = {0.f,0.f};
        int q;
        if (slice == 0) {            // cubic a=0..1                           (256)
            q = 0;   CUBIC(0, 2);
        } else if (slice == 1) {     // cubic a=2..3 + quad a=0..3             (254)
            q = 256; CUBIC(2, 4);
            q = NQ3; QUAD(0, 4);
        } else if (slice == 2) {     // cubic a=4..6 + quad a=4..9             (256)
            q = 452; CUBIC(4, 7);
            q = NQ3 + 58; QUAD(4, 10);
        } else {                     // cubic a=7..15 + quad a=10..15 + linear (202)
            q = 651; CUBIC(7, 16);
            q = NQ3 + 115; QUAD(10, 16);
            q = NQ3 + NQ2;
#pragma unroll
            for (int a = 0; a < 16; ++a) {
                float4 w = cfp[q];
                v2f moA = xvA[a], moB = xvB[a];
                aA0 += moA * w.x; aA1 += moA * w.y; aA2 += moA * w.z; aA3 += moA * w.w;
                aB0 += moB * w.x; aB1 += moB * w.y; aB2 += moB * w.z; aB3 += moB * w.w;
                ++q;
            }
        }
        if (slice > 0) {
            v2f* pp = part[slice - 1][lane];
            pp[0] = aA0; pp[1] = aA1; pp[2] = aA2; pp[3] = aA3;
            pp[4] = aB0; pp[5] = aB1; pp[6] = aB2; pp[7] = aB3;
        }
        __syncthreads();
        if (slice == 0) {
            v2f sA0 = aA0 + part[0][lane][0] + part[1][lane][0] + part[2][lane][0];
            v2f sA1 = aA1 + part[0][lane][1] + part[1][lane][1] + part[2][lane][1];
            v2f sA2 = aA2 + part[0][lane][2] + part[1][lane][2] + part[2][lane][2];
            v2f sA3 = aA3 + part[0][lane][3] + part[1][lane][3] + part[2][lane][3];
            v2f sB0 = aB0 + part[0][lane][4] + part[1][lane][4] + part[2][lane][4];
            v2f sB1 = aB1 + part[0][lane][5] + part[1][lane][5] + part[2][lane][5];
            v2f sB2 = aB2 + part[0][lane][6] + part[1][lane][6] + part[2][lane][6];
            v2f sB3 = aB3 + part[0][lane][7] + part[1][lane][7] + part[2][lane][7];
            if (v0) fout[(size_t)n0 * CC + c] = make_float4(sA0.x, sA1.x, sA2.x, sA3.x);
            if (v1) fout[(size_t)n1 * CC + c] = make_float4(sA0.y, sA1.y, sA2.y, sA3.y);
            if (v2) fout[(size_t)n2 * CC + c] = make_float4(sB0.x, sB1.x, sB2.x, sB3.x);
            if (v3) fout[(size_t)n3 * CC + c] = make_float4(sB0.y, sB1.y, sB2.y, sB3.y);
        }
        __syncthreads();
    }
}

// ---- epilogue linear: 4 nodes per block ----
__global__ __launch_bounds__(256) void k_linear(
    const float4* __restrict__ fin, const float* __restrict__ Wlin0,
    const float* __restrict__ Wlin1, float* __restrict__ out) {
    __shared__ float4 fl[512];
    int t = threadIdx.x;
    fl[t]       = fin[(size_t)blockIdx.x * 512 + t];
    fl[t + 256] = fin[(size_t)blockIdx.x * 512 + t + 256];
    __syncthreads();
    int nh = t >> 7, k = t & 127;
    int n = blockIdx.x * 4 + nh * 2;
    float a0 = 0.f, a1 = 0.f, a2 = 0.f, a3 = 0.f;
    float b0 = 0.f, b1 = 0.f, b2 = 0.f, b3 = 0.f;
#pragma unroll 8
    for (int c = 0; c < CC; ++c) {
        float4 f0 = fl[(nh * 2) * CC + c];
        float4 f1 = fl[(nh * 2 + 1) * CC + c];
        float w0 = Wlin0[c * CC + k];
        float w1 = Wlin1[c * CC + k];
        a0 = fmaf(f0.x, w0, a0); a1 = fmaf(f0.y, w1, a1);
        a2 = fmaf(f0.z, w1, a2); a3 = fmaf(f0.w, w1, a3);
        b0 = fmaf(f1.x, w0, b0); b1 = fmaf(f1.y, w1, b1);
        b2 = fmaf(f1.z, w1, b2); b3 = fmaf(f1.w, w1, b3);
    }
    const float s = 0.08838834764831845f; // 1/sqrt(128)
    float* o = out + (size_t)n * 512;
    o[k] = a0 * s;
    o[128 + 3 * k + 0] = a1 * s;
    o[128 + 3 * k + 1] = a2 * s;
    o[128 + 3 * k + 2] = a3 * s;
    o += 512;
    o[k] = b0 * s;
    o[128 + 3 * k + 0] = b1 * s;
    o[128 + 3 * k + 1] = b2 * s;
    o[128 + 3 * k + 2] = b3 * s;
}

extern "C" void kernel_launch(void* const* d_in, const int* in_sizes, int n_in,
                              void* d_out, int out_size, void* d_ws, size_t ws_size,
                              hipStream_t stream) {
    const float* x     = (const float*)d_in[0];
    const int*   spec  = (const int*)d_in[1];
    const float* U1_0  = (const float*)d_in[2];
    const float* U2_0  = (const float*)d_in[3];
    const float* U3_0  = (const float*)d_in[4];
    const float* W1_0  = (const float*)d_in[5];
    const float* W2_0  = (const float*)d_in[6];
    const float* W3_0  = (const float*)d_in[7];
    const float* Wl_0  = (const float*)d_in[8];
    const float* U1_1  = (const float*)d_in[9];
    const float* U2_1  = (const float*)d_in[10];
    const float* U3_1  = (const float*)d_in[11];
    const float* W1_1  = (const float*)d_in[12];
    const float* W2_1  = (const float*)d_in[13];
    const float* W3_1  = (const float*)d_in[14];
    const float* Wl_1  = (const float*)d_in[15];

    char* ws = (char*)d_ws;
    int*    nodelist = (int*)(ws + NL_OFF);
    int*    counts   = (int*)(ws + CNT_OFF);
    uint2*  call4h   = (uint2*)(ws + CALL_OFF);
    float*  uhat     = (float*)(ws + UHAT_OFF);
    float4* fbuf     = (float4*)(ws + F_OFF);

    k_setup<<<dim3(70), dim3(256), 0, stream>>>(U3_0, U3_1, U2_0, U2_1, U1_0, U1_1,
                                                spec, uhat, nodelist, counts);
    k_fold<<<dim3(880), dim3(256), 0, stream>>>(uhat, W1_0, W2_0, W3_0,
                                                W1_1, W2_1, W3_1, call4h);
    k_eval<<<dim3(640), dim3(256), 0, stream>>>(x, nodelist, counts, call4h, fbuf);
    k_linear<<<dim3(256), dim3(256), 0, stream>>>(fbuf, Wl_0, Wl_1, (float*)d_out);
}

// Round 10
// 83.319 us; speedup vs baseline: 1.0395x; 1.0395x over previous
//
#include <hip/hip_runtime.h>
#include <hip/hip_fp16.h>

typedef float v2f __attribute__((ext_vector_type(2)));

// ---------------- problem constants ----------------
#define NN    1024
#define CC    128
#define NELEM 10
#define NQ3   816
#define NQ2   136
#define NQ    968
#define KP    48     // unified p-dim: 30 (w3) + 12 (w2) + 4 (w1) + 2 pad
#define QT    11     // q-tile per fold block (88 tiles per e)
#define NTILE 88

// ---------------- workspace layout (bytes) ----------------
#define NL_OFF    0          // int[10][1024] = 40960
#define CNT_OFF   40960      // int[10]
#define CALL_OFF  524288     // half4[1280][968] = 9912320 -> 10436608
#define UHAT_OFF  10485760   // float[4][968][48] = 743424
#define F_OFF     20447232   // float4[1024][128] = 2097152 -> 22544384

__device__ __constant__ int d_OFF2[16] = {0,16,31,45,58,70,81,91,100,108,115,121,126,130,133,135};
__device__ __constant__ int d_OFF3[16] = {0,136,256,361,452,530,596,651,696,732,760,781,796,806,812,815};

// ---- setup: blocks 0..63 = sym3, 64..68 = sym2+linear, 69 = species lists ----
__global__ void k_setup(const float* __restrict__ U3_0, const float* __restrict__ U3_1,
                        const float* __restrict__ U2_0, const float* __restrict__ U2_1,
                        const float* __restrict__ U1_0, const float* __restrict__ U1_1,
                        const int* __restrict__ species,
                        float* __restrict__ uhat, int* __restrict__ nodelist,
                        int* __restrict__ counts) {
    if (blockIdx.x < 64) {
        int tid = blockIdx.x * 256 + threadIdx.x;
        int Lout = tid >> 12;
        int r = tid & 4095;
        int a = r >> 8, b = (r >> 4) & 15, m = r & 15;
        if (a > b || b > m) return;
        int q = d_OFF3[a] + (d_OFF2[b] - d_OFF2[a]) + (m - b);
        const float* U = (Lout == 0) ? U3_0 : U3_1;
        int L = (Lout == 0) ? 0 : (Lout - 1);
        int P[6][3] = {{a,b,m},{a,m,b},{b,a,m},{b,m,a},{m,a,b},{m,b,a}};
        float s[30];
#pragma unroll
        for (int p = 0; p < 30; ++p) s[p] = 0.f;
        for (int t = 0; t < 6; ++t) {
            bool dup = false;
            for (int u = 0; u < t; ++u)
                if (P[u][0] == P[t][0] && P[u][1] == P[t][1] && P[u][2] == P[t][2]) dup = true;
            if (dup) continue;
            const float* src = U + ((((L * 16 + P[t][0]) * 16 + P[t][1]) * 16 + P[t][2]) * 30);
#pragma unroll
            for (int p = 0; p < 30; ++p) s[p] += src[p];
        }
        float* dst = uhat + ((size_t)Lout * NQ + q) * KP;
#pragma unroll
        for (int p = 0; p < 30; ++p) dst[p] = s[p];
#pragma unroll
        for (int p = 30; p < KP; ++p) dst[p] = 0.f;
    } else if (blockIdx.x < 69) {
        int tid = (blockIdx.x - 64) * 256 + threadIdx.x;
        if (tid < 1024) {
            int Lout = tid >> 8;
            int r = tid & 255;
            int a = r >> 4, b = r & 15;
            if (a > b) return;
            int q = NQ3 + d_OFF2[a] + (b - a);
            const float* U = (Lout == 0) ? U2_0 : U2_1;
            int L = (Lout == 0) ? 0 : (Lout - 1);
            float* dst = uhat + ((size_t)Lout * NQ + q) * KP;
#pragma unroll
            for (int p = 0; p < 30; ++p) dst[p] = 0.f;
#pragma unroll
            for (int p = 0; p < 12; ++p) {
                float v = U[((L * 16 + a) * 16 + b) * 12 + p];
                if (a != b) v += U[((L * 16 + b) * 16 + a) * 12 + p];
                dst[30 + p] = v;
            }
#pragma unroll
            for (int p = 42; p < KP; ++p) dst[p] = 0.f;
        } else if (tid < 1024 + 64) {
            int s2 = tid - 1024;
            int Lout = s2 >> 4, i = s2 & 15;
            int q = NQ3 + NQ2 + i;
            const float* U = (Lout == 0) ? U1_0 : U1_1;
            int L = (Lout == 0) ? 0 : (Lout - 1);
            float* dst = uhat + ((size_t)Lout * NQ + q) * KP;
#pragma unroll
            for (int p = 0; p < 42; ++p) dst[p] = 0.f;
#pragma unroll
            for (int p = 0; p < 4; ++p) dst[42 + p] = U[(L * 16 + i) * 4 + p];
            dst[46] = 0.f; dst[47] = 0.f;
        }
    } else {
        __shared__ int cnt[NELEM];
        int t = threadIdx.x;
        if (t < NELEM) cnt[t] = 0;
        __syncthreads();
#pragma unroll
        for (int j = 0; j < 4; ++j) {
            int node = t * 4 + j;
            int e = species[node];
            int pos = atomicAdd(&cnt[e], 1);
            nodelist[e * NN + pos] = node;
        }
        __syncthreads();
        if (t < NELEM) counts[t] = cnt[t];
    }
}

// ---- fold: call4h[ec][q] = half4{ dot48(Uhat[L][q][:], Wcat[Lg][:]) } ----
__global__ __launch_bounds__(256) void k_fold(
    const float* __restrict__ uhat,
    const float* __restrict__ W1_0, const float* __restrict__ W2_0, const float* __restrict__ W3_0,
    const float* __restrict__ W1_1, const float* __restrict__ W2_1, const float* __restrict__ W3_1,
    uint2* __restrict__ call4h) {
    __shared__ __align__(16) float uh_lds[4][QT][KP];   // 8448 B
    int e  = blockIdx.x / NTILE;
    int qt = blockIdx.x % NTILE;
    int t = threadIdx.x;
    {
        const float4* src4 = (const float4*)uhat;
        float4* dst4 = (float4*)uh_lds;
        for (int i = t; i < 4 * QT * 12; i += 256) {
            int l = i / (QT * 12);
            int r = i - l * (QT * 12);
            int qloc = r / 12, p4 = r % 12;
            dst4[i] = src4[((size_t)l * NQ + qt * QT + qloc) * 12 + p4];
        }
    }
    int c  = t & 127;
    int qs = t >> 7;
    float wr[2][KP];
#pragma unroll
    for (int p = 0; p < 30; ++p) {
        wr[0][p] = W3_0[(e * 30 + p) * CC + c];
        wr[1][p] = W3_1[(e * 30 + p) * CC + c];
    }
#pragma unroll
    for (int p = 0; p < 12; ++p) {
        wr[0][30 + p] = W2_0[(e * 12 + p) * CC + c];
        wr[1][30 + p] = W2_1[(e * 12 + p) * CC + c];
    }
#pragma unroll
    for (int p = 0; p < 4; ++p) {
        wr[0][42 + p] = W1_0[(e * 4 + p) * CC + c];
        wr[1][42 + p] = W1_1[(e * 4 + p) * CC + c];
    }
    wr[0][46] = wr[0][47] = wr[1][46] = wr[1][47] = 0.f;
    __syncthreads();
    size_t base = ((size_t)e * CC + c) * NQ;
    for (int j = 0; j < 6; ++j) {
        int qloc = qs * 6 + j;
        if (qloc >= QT) break;
        int q = qt * QT + qloc;
        float r[4];
#pragma unroll
        for (int l = 0; l < 4; ++l) {
            const float4* up = (const float4*)uh_lds[l][qloc];
            const float* w = (l == 0) ? wr[0] : wr[1];
            float acc0 = 0.f, acc1 = 0.f, acc2 = 0.f, acc3 = 0.f;
#pragma unroll
            for (int p4 = 0; p4 < 12; ++p4) {
                float4 u = up[p4];
                acc0 = fmaf(u.x, w[p4 * 4 + 0], acc0);
                acc1 = fmaf(u.y, w[p4 * 4 + 1], acc1);
                acc2 = fmaf(u.z, w[p4 * 4 + 2], acc2);
                acc3 = fmaf(u.w, w[p4 * 4 + 3], acc3);
            }
            r[l] = (acc0 + acc1) + (acc2 + acc3);
        }
        __half2 h01 = __floats2half2_rn(r[0], r[1]);
        __half2 h23 = __floats2half2_rn(r[2], r[3]);
        uint2 v;
        v.x = *(unsigned int*)&h01;
        v.y = *(unsigned int*)&h23;
        call4h[base + q] = v;
    }
}

// ---- monomial macros (q pre-set to slice base; f32 coeffs staged in LDS) ----
#define CUBIC(A0, A1) { \
    _Pragma("unroll") for (int a = (A0); a < (A1); ++a) { \
        _Pragma("unroll") for (int b = a; b < 16; ++b) { \
            v2f pab = xv[a] * xv[b]; \
            _Pragma("unroll") for (int m = b; m < 16; ++m) { \
                float4 w = cf_lds[q]; v2f mo = pab * xv[m]; \
                a0 += mo * w.x; a1 += mo * w.y; a2 += mo * w.z; a3 += mo * w.w; ++q; } } } }

#define QUAD(A0, A1) { \
    _Pragma("unroll") for (int a = (A0); a < (A1); ++a) { \
        _Pragma("unroll") for (int b = a; b < 16; ++b) { \
            float4 w = cf_lds[q]; v2f mo = xv[a] * xv[b]; \
            a0 += mo * w.x; a1 += mo * w.y; a2 += mo * w.z; a3 += mo * w.w; ++q; } } }

// ---- polynomial eval: block=(e,c); 4 wave-slices; 2 nodes/thread;
// ---- f16 coeffs upconverted ONCE at stage into f32 LDS (R5 structure + R6 table) ----
__global__ __launch_bounds__(256, 4) void k_eval(
    const float* __restrict__ x, const int* __restrict__ nodelist,
    const int* __restrict__ counts, const uint2* __restrict__ call4h,
    float4* __restrict__ fout) {
    __shared__ __align__(16) float4 cf_lds[NQ];      // 15488 B
    __shared__ __align__(16) v2f part[3][64][4];     // 6144 B
    int ec = blockIdx.x;
    int e = ec >> 7;
    int c = ec & 127;
    int cnt = counts[e];
    const uint2* src = call4h + (size_t)ec * NQ;
    int t = threadIdx.x;
    // stage + upconvert coefficients (coalesced uint2 -> float4)
    for (int i = t; i < NQ; i += 256) {
        uint2 pk = src[i];
        __half2 h01 = *(__half2*)&pk.x, h23 = *(__half2*)&pk.y;
        cf_lds[i] = make_float4(__half2float(h01.x), __half2float(h01.y),
                                __half2float(h23.x), __half2float(h23.y));
    }
    __syncthreads();
    int slice = t >> 6;
    int lane  = t & 63;

    for (int sb = 0; sb < cnt; sb += 128) {
        int i0 = sb + lane * 2, i1 = i0 + 1;
        bool v0i = i0 < cnt, v1i = i1 < cnt;
        int n0 = v0i ? nodelist[e * NN + i0] : 0;
        int n1 = v1i ? nodelist[e * NN + i1] : 0;
        const float4* xp0 = (const float4*)(x + ((size_t)n0 * CC + c) * 16);
        const float4* xp1 = (const float4*)(x + ((size_t)n1 * CC + c) * 16);
        float4 p0 = xp0[0], p1 = xp0[1], p2 = xp0[2], p3 = xp0[3];
        float4 q0 = xp1[0], q1 = xp1[1], q2 = xp1[2], q3 = xp1[3];
        v2f xv[16];
        xv[0]  = v2f{p0.x, q0.x}; xv[1]  = v2f{p0.y, q0.y};
        xv[2]  = v2f{p0.z, q0.z}; xv[3]  = v2f{p0.w, q0.w};
        xv[4]  = v2f{p1.x, q1.x}; xv[5]  = v2f{p1.y, q1.y};
        xv[6]  = v2f{p1.z, q1.z}; xv[7]  = v2f{p1.w, q1.w};
        xv[8]  = v2f{p2.x, q2.x}; xv[9]  = v2f{p2.y, q2.y};
        xv[10] = v2f{p2.z, q2.z}; xv[11] = v2f{p2.w, q2.w};
        xv[12] = v2f{p3.x, q3.x}; xv[13] = v2f{p3.y, q3.y};
        xv[14] = v2f{p3.z, q3.z}; xv[15] = v2f{p3.w, q3.w};
        if (!v0i) {
#pragma unroll
            for (int m = 0; m < 16; ++m) xv[m].x = 0.f;
        }
        if (!v1i) {
#pragma unroll
            for (int m = 0; m < 16; ++m) xv[m].y = 0.f;
        }
        v2f a0 = {0.f, 0.f}, a1 = {0.f, 0.f}, a2 = {0.f, 0.f}, a3 = {0.f, 0.f};
        int q;
        if (slice == 0) {            // cubic a=0..1 : q 0..255                (256)
            q = 0;   CUBIC(0, 2);
        } else if (slice == 1) {     // cubic a=2..3 + quad a=0..3             (254)
            q = 256; CUBIC(2, 4);
            q = NQ3; QUAD(0, 4);
        } else if (slice == 2) {     // cubic a=4..6 + quad a=4..9             (256)
            q = 452; CUBIC(4, 7);
            q = NQ3 + 58; QUAD(4, 10);
        } else {                     // cubic a=7..15 + quad a=10..15 + linear (202)
            q = 651; CUBIC(7, 16);
            q = NQ3 + 115; QUAD(10, 16);
            q = NQ3 + NQ2;
#pragma unroll
            for (int a = 0; a < 16; ++a) {
                float4 w = cf_lds[q]; v2f mo = xv[a];
                a0 += mo * w.x; a1 += mo * w.y; a2 += mo * w.z; a3 += mo * w.w; ++q;
            }
        }
        if (slice > 0) {
            part[slice - 1][lane][0] = a0; part[slice - 1][lane][1] = a1;
            part[slice - 1][lane][2] = a2; part[slice - 1][lane][3] = a3;
        }
        __syncthreads();
        if (slice == 0) {
            v2f s0 = a0 + part[0][lane][0] + part[1][lane][0] + part[2][lane][0];
            v2f s1 = a1 + part[0][lane][1] + part[1][lane][1] + part[2][lane][1];
            v2f s2 = a2 + part[0][lane][2] + part[1][lane][2] + part[2][lane][2];
            v2f s3 = a3 + part[0][lane][3] + part[1][lane][3] + part[2][lane][3];
            if (v0i) fout[(size_t)n0 * CC + c] = make_float4(s0.x, s1.x, s2.x, s3.x);
            if (v1i) fout[(size_t)n1 * CC + c] = make_float4(s0.y, s1.y, s2.y, s3.y);
        }
        __syncthreads();
    }
}

// ---- epilogue linear: 4 nodes per block ----
__global__ __launch_bounds__(256) void k_linear(
    const float4* __restrict__ fin, const float* __restrict__ Wlin0,
    const float* __restrict__ Wlin1, float* __restrict__ out) {
    __shared__ float4 fl[512];
    int t = threadIdx.x;
    fl[t]       = fin[(size_t)blockIdx.x * 512 + t];
    fl[t + 256] = fin[(size_t)blockIdx.x * 512 + t + 256];
    __syncthreads();
    int nh = t >> 7, k = t & 127;
    int n = blockIdx.x * 4 + nh * 2;
    float a0 = 0.f, a1 = 0.f, a2 = 0.f, a3 = 0.f;
    float b0 = 0.f, b1 = 0.f, b2 = 0.f, b3 = 0.f;
#pragma unroll 8
    for (int c = 0; c < CC; ++c) {
        float4 f0 = fl[(nh * 2) * CC + c];
        float4 f1 = fl[(nh * 2 + 1) * CC + c];
        float w0 = Wlin0[c * CC + k];
        float w1 = Wlin1[c * CC + k];
        a0 = fmaf(f0.x, w0, a0); a1 = fmaf(f0.y, w1, a1);
        a2 = fmaf(f0.z, w1, a2); a3 = fmaf(f0.w, w1, a3);
        b0 = fmaf(f1.x, w0, b0); b1 = fmaf(f1.y, w1, b1);
        b2 = fmaf(f1.z, w1, b2); b3 = fmaf(f1.w, w1, b3);
    }
    const float s = 0.08838834764831845f; // 1/sqrt(128)
    float* o = out + (size_t)n * 512;
    o[k] = a0 * s;
    o[128 + 3 * k + 0] = a1 * s;
    o[128 + 3 * k + 1] = a2 * s;
    o[128 + 3 * k + 2] = a3 * s;
    o += 512;
    o[k] = b0 * s;
    o[128 + 3 * k + 0] = b1 * s;
    o[128 + 3 * k + 1] = b2 * s;
    o[128 + 3 * k + 2] = b3 * s;
}

extern "C" void kernel_launch(void* const* d_in, const int* in_sizes, int n_in,
                              void* d_out, int out_size, void* d_ws, size_t ws_size,
                              hipStream_t stream) {
    const float* x     = (const float*)d_in[0];
    const int*   spec  = (const int*)d_in[1];
    const float* U1_0  = (const float*)d_in[2];
    const float* U2_0  = (const float*)d_in[3];
    const float* U3_0  = (const float*)d_in[4];
    const float* W1_0  = (const float*)d_in[5];
    const float* W2_0  = (const float*)d_in[6];
    const float* W3_0  = (const float*)d_in[7];
    const float* Wl_0  = (const float*)d_in[8];
    const float* U1_1  = (const float*)d_in[9];
    const float* U2_1  = (const float*)d_in[10];
    const float* U3_1  = (const float*)d_in[11];
    const float* W1_1  = (const float*)d_in[12];
    const float* W2_1  = (const float*)d_in[13];
    const float* W3_1  = (const float*)d_in[14];
    const float* Wl_1  = (const float*)d_in[15];

    char* ws = (char*)d_ws;
    int*    nodelist = (int*)(ws + NL_OFF);
    int*    counts   = (int*)(ws + CNT_OFF);
    uint2*  call4h   = (uint2*)(ws + CALL_OFF);
    float*  uhat     = (float*)(ws + UHAT_OFF);
    float4* fbuf     = (float4*)(ws + F_OFF);

    k_setup<<<dim3(70), dim3(256), 0, stream>>>(U3_0, U3_1, U2_0, U2_1, U1_0, U1_1,
                                                spec, uhat, nodelist, counts);
    k_fold<<<dim3(880), dim3(256), 0, stream>>>(uhat, W1_0, W2_0, W3_0,
                                                W1_1, W2_1, W3_1, call4h);
    k_eval<<<dim3(1280), dim3(256), 0, stream>>>(x, nodelist, counts, call4h, fbuf);
    k_linear<<<dim3(256), dim3(256), 0, stream>>>(fbuf, Wl_0, Wl_1, (float*)d_out);
}

// Round 11
// 75.130 us; speedup vs baseline: 1.1528x; 1.1090x over previous
//
#include <hip/hip_runtime.h>
#include <hip/hip_fp16.h>

typedef float v2f __attribute__((ext_vector_type(2)));

// ---------------- problem constants ----------------
#define NN    1024
#define CC    128
#define NELEM 10
#define NQ3   816
#define NQ2   136
#define NQ    968
#define KP    48     // unified p-dim: 30 (w3) + 12 (w2) + 4 (w1) + 2 pad
#define QT    11     // q-tile per fold block (88 tiles per e)
#define NTILE 88

// ---- slot-padded coefficient layout: every (a,b) run starts at an even slot ----
constexpr int rnd2c(int s) { return (s + 1) & ~1; }
constexpr int cub_start(int A, int B) {
    int s = 0;
    for (int a = 0; a < 16; ++a)
        for (int b = a; b < 16; ++b) {
            s = rnd2c(s);
            if (a == A && b == B) return s;
            s += 16 - b;
        }
    return rnd2c(s);                 // A>=16: end of cubic region (even)
}
constexpr int quad_start(int A) {
    int s = cub_start(16, 0);
    for (int a = 0; a < 16; ++a) {
        s = rnd2c(s);
        if (a == A) return s;
        s += 16 - a;
    }
    return rnd2c(s);
}
constexpr int LIN_START = quad_start(16);
constexpr int NSLOT = (LIN_START + 16 + 1) & ~1;
static_assert(cub_start(0, 0) == 0, "layout");
static_assert(NSLOT <= 1152, "lds budget");

struct SlotTab {
    unsigned short t[NQ];
    constexpr SlotTab() : t{} {
        int q = 0, s = 0;
        for (int a = 0; a < 16; ++a)
            for (int b = a; b < 16; ++b) {
                s = rnd2c(s);
                for (int m = b; m < 16; ++m) t[q++] = (unsigned short)(s++);
            }
        for (int a = 0; a < 16; ++a) {
            s = rnd2c(s);
            for (int b = a; b < 16; ++b) t[q++] = (unsigned short)(s++);
        }
        s = rnd2c(s);
        for (int i = 0; i < 16; ++i) t[q++] = (unsigned short)(s++);
    }
};
__device__ __constant__ SlotTab kSlot = SlotTab();

// ---------------- workspace layout (bytes) ----------------
#define NL_OFF    0          // int[10][1024] = 40960
#define CNT_OFF   40960      // int[10]
#define CALL_OFF  524288     // uint2[1280][NSLOT] ~ 10.8 MB
#define UHAT_OFF  12582912   // float[4][968][48] = 743424
#define F_OFF     20447232   // float4[1024][128] = 2097152 -> 22544384

__device__ __constant__ int d_OFF2[16] = {0,16,31,45,58,70,81,91,100,108,115,121,126,130,133,135};
__device__ __constant__ int d_OFF3[16] = {0,136,256,361,452,530,596,651,696,732,760,781,796,806,812,815};

// ---- setup: blocks 0..63 = sym3, 64..68 = sym2+linear, 69 = species lists ----
__global__ void k_setup(const float* __restrict__ U3_0, const float* __restrict__ U3_1,
                        const float* __restrict__ U2_0, const float* __restrict__ U2_1,
                        const float* __restrict__ U1_0, const float* __restrict__ U1_1,
                        const int* __restrict__ species,
                        float* __restrict__ uhat, int* __restrict__ nodelist,
                        int* __restrict__ counts) {
    if (blockIdx.x < 64) {
        int tid = blockIdx.x * 256 + threadIdx.x;
        int Lout = tid >> 12;
        int r = tid & 4095;
        int a = r >> 8, b = (r >> 4) & 15, m = r & 15;
        if (a > b || b > m) return;
        int q = d_OFF3[a] + (d_OFF2[b] - d_OFF2[a]) + (m - b);
        const float* U = (Lout == 0) ? U3_0 : U3_1;
        int L = (Lout == 0) ? 0 : (Lout - 1);
        int P[6][3] = {{a,b,m},{a,m,b},{b,a,m},{b,m,a},{m,a,b},{m,b,a}};
        float s[30];
#pragma unroll
        for (int p = 0; p < 30; ++p) s[p] = 0.f;
        for (int t = 0; t < 6; ++t) {
            bool dup = false;
            for (int u = 0; u < t; ++u)
                if (P[u][0] == P[t][0] && P[u][1] == P[t][1] && P[u][2] == P[t][2]) dup = true;
            if (dup) continue;
            const float* src = U + ((((L * 16 + P[t][0]) * 16 + P[t][1]) * 16 + P[t][2]) * 30);
#pragma unroll
            for (int p = 0; p < 30; ++p) s[p] += src[p];
        }
        float* dst = uhat + ((size_t)Lout * NQ + q) * KP;
#pragma unroll
        for (int p = 0; p < 30; ++p) dst[p] = s[p];
#pragma unroll
        for (int p = 30; p < KP; ++p) dst[p] = 0.f;
    } else if (blockIdx.x < 69) {
        int tid = (blockIdx.x - 64) * 256 + threadIdx.x;
        if (tid < 1024) {
            int Lout = tid >> 8;
            int r = tid & 255;
            int a = r >> 4, b = r & 15;
            if (a > b) return;
            int q = NQ3 + d_OFF2[a] + (b - a);
            const float* U = (Lout == 0) ? U2_0 : U2_1;
            int L = (Lout == 0) ? 0 : (Lout - 1);
            float* dst = uhat + ((size_t)Lout * NQ + q) * KP;
#pragma unroll
            for (int p = 0; p < 30; ++p) dst[p] = 0.f;
#pragma unroll
            for (int p = 0; p < 12; ++p) {
                float v = U[((L * 16 + a) * 16 + b) * 12 + p];
                if (a != b) v += U[((L * 16 + b) * 16 + a) * 12 + p];
                dst[30 + p] = v;
            }
#pragma unroll
            for (int p = 42; p < KP; ++p) dst[p] = 0.f;
        } else if (tid < 1024 + 64) {
            int s2 = tid - 1024;
            int Lout = s2 >> 4, i = s2 & 15;
            int q = NQ3 + NQ2 + i;
            const float* U = (Lout == 0) ? U1_0 : U1_1;
            int L = (Lout == 0) ? 0 : (Lout - 1);
            float* dst = uhat + ((size_t)Lout * NQ + q) * KP;
#pragma unroll
            for (int p = 0; p < 42; ++p) dst[p] = 0.f;
#pragma unroll
            for (int p = 0; p < 4; ++p) dst[42 + p] = U[(L * 16 + i) * 4 + p];
            dst[46] = 0.f; dst[47] = 0.f;
        }
    } else {
        __shared__ int cnt[NELEM];
        int t = threadIdx.x;
        if (t < NELEM) cnt[t] = 0;
        __syncthreads();
#pragma unroll
        for (int j = 0; j < 4; ++j) {
            int node = t * 4 + j;
            int e = species[node];
            int pos = atomicAdd(&cnt[e], 1);
            nodelist[e * NN + pos] = node;
        }
        __syncthreads();
        if (t < NELEM) counts[t] = cnt[t];
    }
}

// ---- fold: call4h[ec][slot(q)] = half4{ dot48(Uhat[L][q][:], Wcat[Lg][:]) } ----
__global__ __launch_bounds__(256) void k_fold(
    const float* __restrict__ uhat,
    const float* __restrict__ W1_0, const float* __restrict__ W2_0, const float* __restrict__ W3_0,
    const float* __restrict__ W1_1, const float* __restrict__ W2_1, const float* __restrict__ W3_1,
    uint2* __restrict__ call4h) {
    __shared__ __align__(16) float uh_lds[4][QT][KP];   // 8448 B
    int e  = blockIdx.x / NTILE;
    int qt = blockIdx.x % NTILE;
    int t = threadIdx.x;
    {
        const float4* src4 = (const float4*)uhat;
        float4* dst4 = (float4*)uh_lds;
        for (int i = t; i < 4 * QT * 12; i += 256) {
            int l = i / (QT * 12);
            int r = i - l * (QT * 12);
            int qloc = r / 12, p4 = r % 12;
            dst4[i] = src4[((size_t)l * NQ + qt * QT + qloc) * 12 + p4];
        }
    }
    int c  = t & 127;
    int qs = t >> 7;
    float wr[2][KP];
#pragma unroll
    for (int p = 0; p < 30; ++p) {
        wr[0][p] = W3_0[(e * 30 + p) * CC + c];
        wr[1][p] = W3_1[(e * 30 + p) * CC + c];
    }
#pragma unroll
    for (int p = 0; p < 12; ++p) {
        wr[0][30 + p] = W2_0[(e * 12 + p) * CC + c];
        wr[1][30 + p] = W2_1[(e * 12 + p) * CC + c];
    }
#pragma unroll
    for (int p = 0; p < 4; ++p) {
        wr[0][42 + p] = W1_0[(e * 4 + p) * CC + c];
        wr[1][42 + p] = W1_1[(e * 4 + p) * CC + c];
    }
    wr[0][46] = wr[0][47] = wr[1][46] = wr[1][47] = 0.f;
    __syncthreads();
    size_t base = ((size_t)e * CC + c) * NSLOT;
    for (int j = 0; j < 6; ++j) {
        int qloc = qs * 6 + j;
        if (qloc >= QT) break;
        int q = qt * QT + qloc;
        float r[4];
#pragma unroll
        for (int l = 0; l < 4; ++l) {
            const float4* up = (const float4*)uh_lds[l][qloc];
            const float* w = (l == 0) ? wr[0] : wr[1];
            float acc0 = 0.f, acc1 = 0.f, acc2 = 0.f, acc3 = 0.f;
#pragma unroll
            for (int p4 = 0; p4 < 12; ++p4) {
                float4 u = up[p4];
                acc0 = fmaf(u.x, w[p4 * 4 + 0], acc0);
                acc1 = fmaf(u.y, w[p4 * 4 + 1], acc1);
                acc2 = fmaf(u.z, w[p4 * 4 + 2], acc2);
                acc3 = fmaf(u.w, w[p4 * 4 + 3], acc3);
            }
            r[l] = (acc0 + acc1) + (acc2 + acc3);
        }
        __half2 h01 = __floats2half2_rn(r[0], r[1]);
        __half2 h23 = __floats2half2_rn(r[2], r[3]);
        uint2 v;
        v.x = *(unsigned int*)&h01;
        v.y = *(unsigned int*)&h23;
        call4h[base + kSlot.t[q]] = v;
    }
}

// ---- paired-read monomial macros: 2 slots (= 2 monomials) per ds_read_b128 ----
#define PAIR_FMA(MO1, MO2) { \
    uint4 pk4 = *(const uint4*)(cf16 + q); \
    __half2 ha = *(__half2*)&pk4.x, hb = *(__half2*)&pk4.y; \
    __half2 hc = *(__half2*)&pk4.z, hd = *(__half2*)&pk4.w; \
    v2f mo1 = (MO1), mo2 = (MO2); \
    a0 += mo1 * __half2float(ha.x); a1 += mo1 * __half2float(ha.y); \
    a2 += mo1 * __half2float(hb.x); a3 += mo1 * __half2float(hb.y); \
    a0 += mo2 * __half2float(hc.x); a1 += mo2 * __half2float(hc.y); \
    a2 += mo2 * __half2float(hd.x); a3 += mo2 * __half2float(hd.y); \
    q += 2; }

#define ONE_FMA(MO) { \
    uint2 pk2 = *(const uint2*)(cf16 + q); \
    __half2 ha = *(__half2*)&pk2.x, hb = *(__half2*)&pk2.y; \
    v2f mo = (MO); \
    a0 += mo * __half2float(ha.x); a1 += mo * __half2float(ha.y); \
    a2 += mo * __half2float(hb.x); a3 += mo * __half2float(hb.y); \
    q += 1; }

#define CUBIC(A0, A1) { \
    _Pragma("unroll") for (int a = (A0); a < (A1); ++a) { \
        _Pragma("unroll") for (int b = a; b < 16; ++b) { \
            q = (q + 1) & ~1; \
            v2f pab = xv[a] * xv[b]; \
            int m = b; \
            _Pragma("unroll") for (; m + 1 < 16; m += 2) PAIR_FMA(pab * xv[m], pab * xv[m + 1]); \
            if (m < 16) ONE_FMA(pab * xv[m]); \
        } } }

#define QUAD(A0, A1) { \
    _Pragma("unroll") for (int a = (A0); a < (A1); ++a) { \
        q = (q + 1) & ~1; \
        int b = a; \
        _Pragma("unroll") for (; b + 1 < 16; b += 2) PAIR_FMA(xv[a] * xv[b], xv[a] * xv[b + 1]); \
        if (b < 16) ONE_FMA(xv[a] * xv[b]); \
    } }

// ---- polynomial eval: block=(e,c); 4 wave-slices; 2 nodes/thread;
// ---- f16 coeffs in LDS, 2 monomials per ds_read_b128 (slot-padded layout) ----
__global__ __launch_bounds__(256, 3) void k_eval(
    const float* __restrict__ x, const int* __restrict__ nodelist,
    const int* __restrict__ counts, const uint2* __restrict__ call4h,
    float4* __restrict__ fout) {
    __shared__ __align__(16) uint2 cf16[NSLOT];      // ~8.4 KB
    __shared__ __align__(16) v2f part[3][64][4];     // 6144 B
    int ec = blockIdx.x;
    int e = ec >> 7;
    int c = ec & 127;
    int cnt = counts[e];
    const uint2* src = call4h + (size_t)ec * NSLOT;
    int t = threadIdx.x;
    int slice = t >> 6;
    int lane  = t & 63;

    // first-batch node ids issued before staging (vmem overlap)
    int i0 = lane * 2, i1 = i0 + 1;
    bool v0i = i0 < cnt, v1i = i1 < cnt;
    int n0 = v0i ? nodelist[e * NN + i0] : 0;
    int n1 = v1i ? nodelist[e * NN + i1] : 0;

    // stage coefficients (coalesced uint4 = 2 slots each)
    for (int i = t; i < NSLOT / 2; i += 256)
        ((uint4*)cf16)[i] = ((const uint4*)src)[i];

    for (int sb = 0; sb < cnt; sb += 128) {
        if (sb > 0) {
            i0 = sb + lane * 2; i1 = i0 + 1;
            v0i = i0 < cnt; v1i = i1 < cnt;
            n0 = v0i ? nodelist[e * NN + i0] : 0;
            n1 = v1i ? nodelist[e * NN + i1] : 0;
        }
        const float4* xp0 = (const float4*)(x + ((size_t)n0 * CC + c) * 16);
        const float4* xp1 = (const float4*)(x + ((size_t)n1 * CC + c) * 16);
        float4 p0 = xp0[0], p1 = xp0[1], p2 = xp0[2], p3 = xp0[3];
        float4 q0 = xp1[0], q1 = xp1[1], q2 = xp1[2], q3 = xp1[3];
        if (sb == 0) __syncthreads();   // staging visible before cf16 reads
        v2f xv[16];
        xv[0]  = v2f{p0.x, q0.x}; xv[1]  = v2f{p0.y, q0.y};
        xv[2]  = v2f{p0.z, q0.z}; xv[3]  = v2f{p0.w, q0.w};
        xv[4]  = v2f{p1.x, q1.x}; xv[5]  = v2f{p1.y, q1.y};
        xv[6]  = v2f{p1.z, q1.z}; xv[7]  = v2f{p1.w, q1.w};
        xv[8]  = v2f{p2.x, q2.x}; xv[9]  = v2f{p2.y, q2.y};
        xv[10] = v2f{p2.z, q2.z}; xv[11] = v2f{p2.w, q2.w};
        xv[12] = v2f{p3.x, q3.x}; xv[13] = v2f{p3.y, q3.y};
        xv[14] = v2f{p3.z, q3.z}; xv[15] = v2f{p3.w, q3.w};
        if (!v0i) {
#pragma unroll
            for (int m = 0; m < 16; ++m) xv[m].x = 0.f;
        }
        if (!v1i) {
#pragma unroll
            for (int m = 0; m < 16; ++m) xv[m].y = 0.f;
        }
        v2f a0 = {0.f, 0.f}, a1 = {0.f, 0.f}, a2 = {0.f, 0.f}, a3 = {0.f, 0.f};
        int q;
        if (slice == 0) {            // cubic a=0..1                           (256 q)
            q = cub_start(0, 0); CUBIC(0, 2);
        } else if (slice == 1) {     // cubic a=2..3 + quad a=0..3             (254 q)
            q = cub_start(2, 2); CUBIC(2, 4);
            q = quad_start(0);   QUAD(0, 4);
        } else if (slice == 2) {     // cubic a=4..6 + quad a=4..9             (256 q)
            q = cub_start(4, 4); CUBIC(4, 7);
            q = quad_start(4);   QUAD(4, 10);
        } else {                     // cubic a=7..15 + quad a=10..15 + linear (202 q)
            q = cub_start(7, 7); CUBIC(7, 16);
            q = quad_start(10);  QUAD(10, 16);
            q = LIN_START;
#pragma unroll
            for (int a = 0; a < 16; a += 2) PAIR_FMA(xv[a], xv[a + 1]);
        }
        if (slice > 0) {
            part[slice - 1][lane][0] = a0; part[slice - 1][lane][1] = a1;
            part[slice - 1][lane][2] = a2; part[slice - 1][lane][3] = a3;
        }
        __syncthreads();
        if (slice == 0) {
            v2f s0 = a0 + part[0][lane][0] + part[1][lane][0] + part[2][lane][0];
            v2f s1 = a1 + part[0][lane][1] + part[1][lane][1] + part[2][lane][1];
            v2f s2 = a2 + part[0][lane][2] + part[1][lane][2] + part[2][lane][2];
            v2f s3 = a3 + part[0][lane][3] + part[1][lane][3] + part[2][lane][3];
            if (v0i) fout[(size_t)n0 * CC + c] = make_float4(s0.x, s1.x, s2.x, s3.x);
            if (v1i) fout[(size_t)n1 * CC + c] = make_float4(s0.y, s1.y, s2.y, s3.y);
        }
        __syncthreads();
    }
}

// ---- epilogue linear: 4 nodes per block ----
__global__ __launch_bounds__(256) void k_linear(
    const float4* __restrict__ fin, const float* __restrict__ Wlin0,
    const float* __restrict__ Wlin1, float* __restrict__ out) {
    __shared__ float4 fl[512];
    int t = threadIdx.x;
    fl[t]       = fin[(size_t)blockIdx.x * 512 + t];
    fl[t + 256] = fin[(size_t)blockIdx.x * 512 + t + 256];
    __syncthreads();
    int nh = t >> 7, k = t & 127;
    int n = blockIdx.x * 4 + nh * 2;
    float a0 = 0.f, a1 = 0.f, a2 = 0.f, a3 = 0.f;
    float b0 = 0.f, b1 = 0.f, b2 = 0.f, b3 = 0.f;
#pragma unroll 8
    for (int c = 0; c < CC; ++c) {
        float4 f0 = fl[(nh * 2) * CC + c];
        float4 f1 = fl[(nh * 2 + 1) * CC + c];
        float w0 = Wlin0[c * CC + k];
        float w1 = Wlin1[c * CC + k];
        a0 = fmaf(f0.x, w0, a0); a1 = fmaf(f0.y, w1, a1);
        a2 = fmaf(f0.z, w1, a2); a3 = fmaf(f0.w, w1, a3);
        b0 = fmaf(f1.x, w0, b0); b1 = fmaf(f1.y, w1, b1);
        b2 = fmaf(f1.z, w1, b2); b3 = fmaf(f1.w, w1, b3);
    }
    const float s = 0.08838834764831845f; // 1/sqrt(128)
    float* o = out + (size_t)n * 512;
    o[k] = a0 * s;
    o[128 + 3 * k + 0] = a1 * s;
    o[128 + 3 * k + 1] = a2 * s;
    o[128 + 3 * k + 2] = a3 * s;
    o += 512;
    o[k] = b0 * s;
    o[128 + 3 * k + 0] = b1 * s;
    o[128 + 3 * k + 1] = b2 * s;
    o[128 + 3 * k + 2] = b3 * s;
}

extern "C" void kernel_launch(void* const* d_in, const int* in_sizes, int n_in,
                              void* d_out, int out_size, void* d_ws, size_t ws_size,
                              hipStream_t stream) {
    const float* x     = (const float*)d_in[0];
    const int*   spec  = (const int*)d_in[1];
    const float* U1_0  = (const float*)d_in[2];
    const float* U2_0  = (const float*)d_in[3];
    const float* U3_0  = (const float*)d_in[4];
    const float* W1_0  = (const float*)d_in[5];
    const float* W2_0  = (const float*)d_in[6];
    const float* W3_0  = (const float*)d_in[7];
    const float* Wl_0  = (const float*)d_in[8];
    const float* U1_1  = (const float*)d_in[9];
    const float* U2_1  = (const float*)d_in[10];
    const float* U3_1  = (const float*)d_in[11];
    const float* W1_1  = (const float*)d_in[12];
    const float* W2_1  = (const float*)d_in[13];
    const float* W3_1  = (const float*)d_in[14];
    const float* Wl_1  = (const float*)d_in[15];

    char* ws = (char*)d_ws;
    int*    nodelist = (int*)(ws + NL_OFF);
    int*    counts   = (int*)(ws + CNT_OFF);
    uint2*  call4h   = (uint2*)(ws + CALL_OFF);
    float*  uhat     = (float*)(ws + UHAT_OFF);
    float4* fbuf     = (float4*)(ws + F_OFF);

    k_setup<<<dim3(70), dim3(256), 0, stream>>>(U3_0, U3_1, U2_0, U2_1, U1_0, U1_1,
                                                spec, uhat, nodelist, counts);
    k_fold<<<dim3(880), dim3(256), 0, stream>>>(uhat, W1_0, W2_0, W3_0,
                                                W1_1, W2_1, W3_1, call4h);
    k_eval<<<dim3(1280), dim3(256), 0, stream>>>(x, nodelist, counts, call4h, fbuf);
    k_linear<<<dim3(256), dim3(256), 0, stream>>>(fbuf, Wl_0, Wl_1, (float*)d_out);
}